// Round 3
// baseline (182.405 us; speedup 1.0000x reference)
//
#include <hip/hip_runtime.h>

#define NB 32      // batch
#define NJ 8192    // h*w*Nin
#define NC 10      // NUM_CAPS
#define CL 16      // CAP_LEN
#define KK 160     // NC*CL
#define JT 16      // j per block
#define NTHR 640   // 40 k4 x 16 jj  (t = k4*16 + jj)
#define BCH 4      // batches per barrier pair
#define REP 8      // s_part replicas (atomic contention spread)
#define EPSQ 1e-20f

// in-wave sum over jj = lane&15, pure VALU via DPP adds
template<int CTRL>
__device__ __forceinline__ float dpp_add(float v) {
    int s = __builtin_amdgcn_update_dpp(0, __float_as_int(v), CTRL, 0xF, 0xF, true);
    return v + __int_as_float(s);
}
__device__ __forceinline__ float red16(float v) {
    v = dpp_add<0xB1>(v);    // quad_perm [1,0,3,2]  : xor 1
    v = dpp_add<0x4E>(v);    // quad_perm [2,3,0,1]  : xor 2
    v = dpp_add<0x141>(v);   // row_half_mirror      : pairs quads 0<->1, 2<->3
    v = dpp_add<0x140>(v);   // row_mirror           : pairs half-rows
    return v;
}

// One routing iteration. W in registers (32 VGPR), u stays in registers,
// j-reduction via DPP, 2 barriers per 4-batch chunk (0 barriers for R=0).
// Linearity trick: logits b_r[b,j,n] = u . (v0+...+v_{r-1}) -> carry only vsum.
template<int R>
__global__ __launch_bounds__(NTHR, 5)
void rout_kernel(const float* __restrict__ x, const float* __restrict__ W,
                 const float* __restrict__ vsum, float* __restrict__ s_part) {
    __shared__ float xs[NB][JT][10];   // 20 KB, pad->b64 reads hit 32 banks once
    __shared__ float vsl[NB][KK];      // 20 KB
    __shared__ float bl[BCH][JT][12];  // 3 KB
    __shared__ float cl[BCH][JT][12];  // 3 KB

    const int t   = threadIdx.x;
    const int jj  = t & 15;            // j within tile = lane bits 0..3
    const int k4  = t >> 4;            // float4 chunk of k, 0..39
    const int nB  = k4 >> 2;           // cap index = wave index
    const int c4  = k4 & 3;            // c-quad within cap = lane bits 4..5
    const int j0  = blockIdx.x * JT;
    const int rep = blockIdx.x & (REP - 1);

    // ---- W -> registers, once per dispatch ----
    float4 w[8];
    {
        const float* wp = W + ((size_t)(j0 + jj) * 8) * KK + (k4 << 2);
        #pragma unroll
        for (int i = 0; i < 8; ++i)
            w[i] = *(const float4*)(wp + i * KK);
    }
    // ---- x tile (all 32 b) -> LDS ----
    for (int e4 = t; e4 < NB * JT * 2; e4 += NTHR) {
        const int b = e4 >> 5, rem = e4 & 31, jx = rem >> 1, hf = rem & 1;
        const float4 v = *(const float4*)(x + ((size_t)b * NJ + j0 + jx) * 8 + hf * 4);
        float* d = &xs[b][jx][hf * 4];
        d[0] = v.x; d[1] = v.y; d[2] = v.z; d[3] = v.w;
    }
    // ---- vsum -> LDS (R>0) ----
    if (R > 0) {
        for (int f4 = t; f4 < NB * 40; f4 += NTHR) {
            const int b = f4 / 40, rem = f4 % 40;
            *(float4*)&vsl[b][rem * 4] = *(const float4*)(vsum + (size_t)b * KK + rem * 4);
        }
    }
    __syncthreads();

    for (int b0 = 0; b0 < NB; b0 += BCH) {
        // ---- A: u quads for BCH batches, in registers ----
        float4 u[BCH];
        #pragma unroll
        for (int bc = 0; bc < BCH; ++bc) {
            const int b = b0 + bc;
            float4 acc = {0.f, 0.f, 0.f, 0.f};
            #pragma unroll
            for (int seg = 0; seg < 4; ++seg) {
                const float2 xv = *(const float2*)&xs[b][jj][seg * 2];
                const float4 wa = w[seg * 2], wb = w[seg * 2 + 1];
                acc.x = fmaf(wa.x, xv.x, acc.x); acc.y = fmaf(wa.y, xv.x, acc.y);
                acc.z = fmaf(wa.z, xv.x, acc.z); acc.w = fmaf(wa.w, xv.x, acc.w);
                acc.x = fmaf(wb.x, xv.y, acc.x); acc.y = fmaf(wb.y, xv.y, acc.y);
                acc.z = fmaf(wb.z, xv.y, acc.z); acc.w = fmaf(wb.w, xv.y, acc.w);
            }
            u[bc] = acc;
        }

        if (R > 0) {
            // ---- B: logit = u . vsum, reduce over c4 (lane bits 4,5) ----
            #pragma unroll
            for (int bc = 0; bc < BCH; ++bc) {
                const int b = b0 + bc;
                const float4 vv = *(const float4*)&vsl[b][k4 * 4];
                float bd = u[bc].x * vv.x + u[bc].y * vv.y
                         + u[bc].z * vv.z + u[bc].w * vv.w;
                bd += __shfl_xor(bd, 16);
                bd += __shfl_xor(bd, 32);
                if (c4 == 0) bl[bc][jj][nB] = bd;
            }
            __syncthreads();
            // ---- C: softmax over n, all 640 = 4bc x 16jj x 10nn threads ----
            {
                const int bcC = t / 160, rem = t % 160;
                const int jjC = rem & 15, nn = rem >> 4;
                float m = -1e30f;
                #pragma unroll
                for (int q = 0; q < NC; ++q) m = fmaxf(m, bl[bcC][jjC][q]);
                float sum = 0.f;
                #pragma unroll
                for (int q = 0; q < NC; ++q) sum += __expf(bl[bcC][jjC][q] - m);
                cl[bcC][jjC][nn] = __expf(bl[bcC][jjC][nn] - m) / sum;
            }
            __syncthreads();
        }

        // ---- D: s partial = sum_jj c*u via DPP, one atomic quad per (b,k4) ----
        #pragma unroll
        for (int bc = 0; bc < BCH; ++bc) {
            const int b = b0 + bc;
            const float c = (R == 0) ? 0.1f : cl[bc][jj][nB];
            const float sx = red16(u[bc].x * c);
            const float sy = red16(u[bc].y * c);
            const float sz = red16(u[bc].z * c);
            const float sw = red16(u[bc].w * c);
            if (jj == 0) {
                float* sp = s_part + ((size_t)rep * NB + b) * KK + (k4 << 2);
                atomicAdd(sp + 0, sx); atomicAdd(sp + 1, sy);
                atomicAdd(sp + 2, sz); atomicAdd(sp + 3, sw);
            }
        }
        // no trailing barrier needed: next chunk's bl writes come after this
        // chunk's C (bl reads) by barrier order; cl writes after barrier#1(g+1).
    }
}

// Sum replicas, +bias, squash. MODE: 0 vsum=v, 1 vsum+=v, 2 out=v. Re-zeroes s_part.
template<int MODE>
__global__ __launch_bounds__(256)
void squash_kernel(float* __restrict__ s_part, const float* __restrict__ biases,
                   float* __restrict__ vsum, float* __restrict__ out) {
    const int t = blockIdx.x * blockDim.x + threadIdx.x;   // 0..5119
    if (t >= NB * KK) return;
    float s = 0.f;
    #pragma unroll
    for (int r = 0; r < REP; ++r) {
        s += s_part[(size_t)r * (NB * KK) + t];
        s_part[(size_t)r * (NB * KK) + t] = 0.f;
    }
    s += biases[t % KK];
    const float n = fabsf(s);
    const float v = (n * n) / (1.f + n * n) / (n + EPSQ) * s;
    if (MODE == 2)      out[t]   = v;
    else if (MODE == 1) vsum[t] += v;
    else                vsum[t]  = v;
}

extern "C" void kernel_launch(void* const* d_in, const int* in_sizes, int n_in,
                              void* d_out, int out_size, void* d_ws, size_t ws_size,
                              hipStream_t stream) {
    const float* x      = (const float*)d_in[0];
    const float* W      = (const float*)d_in[1];
    const float* biases = (const float*)d_in[2];
    float* out    = (float*)d_out;
    float* s_part = (float*)d_ws;                    // [REP][NB*KK]
    float* vsum   = s_part + (size_t)REP * NB * KK;  // [NB*KK]

    hipMemsetAsync(s_part, 0, (size_t)REP * NB * KK * sizeof(float), stream);

    const dim3 grid(NJ / JT);   // 512 blocks = 2/CU
    rout_kernel<0><<<grid, NTHR, 0, stream>>>(x, W, nullptr, s_part);
    squash_kernel<0><<<20, 256, 0, stream>>>(s_part, biases, vsum, out);

    rout_kernel<1><<<grid, NTHR, 0, stream>>>(x, W, vsum, s_part);
    squash_kernel<1><<<20, 256, 0, stream>>>(s_part, biases, vsum, out);

    rout_kernel<2><<<grid, NTHR, 0, stream>>>(x, W, vsum, s_part);
    squash_kernel<2><<<20, 256, 0, stream>>>(s_part, biases, vsum, out);
}

// Round 4
// 125.985 us; speedup vs baseline: 1.4478x; 1.4478x over previous
//
#include <hip/hip_runtime.h>

#define NB 32      // batch
#define NJ 8192    // h*w*Nin
#define NC 10      // NUM_CAPS
#define CL 16      // CAP_LEN
#define KK 160     // NC*CL
#define JT 16      // j per block
#define NTHR 640   // 40 k4 x 16 jj  (t = k4*16 + jj)
#define BCH 4      // batches per barrier pair
#define NPART (NJ / JT)   // 512 partial slots (store path)
#define REP 8             // replicas (atomic fallback path)
#define EPSQ 1e-20f

// in-wave sum over jj = lane&15, pure VALU via DPP adds
template<int CTRL>
__device__ __forceinline__ float dpp_add(float v) {
    int s = __builtin_amdgcn_update_dpp(0, __float_as_int(v), CTRL, 0xF, 0xF, true);
    return v + __int_as_float(s);
}
__device__ __forceinline__ float red16(float v) {
    v = dpp_add<0xB1>(v);    // quad_perm xor1
    v = dpp_add<0x4E>(v);    // quad_perm xor2
    v = dpp_add<0x141>(v);   // row_half_mirror
    v = dpp_add<0x140>(v);   // row_mirror
    return v;
}

// One routing iteration. W in registers, u in registers, j-reduce via DPP.
// ATOM=false: per-block partial quad STORED (no atomics). ATOM=true: legacy
// replicated atomicAdd path (ws-size fallback).
template<int R, bool ATOM>
__global__ __launch_bounds__(NTHR, 5)
void rout_kernel(const float* __restrict__ x, const float* __restrict__ W,
                 const float* __restrict__ vsum, float* __restrict__ sdst) {
    __shared__ float xs[NB][JT][10];   // 20 KB, pad -> b64 reads conflict-free
    __shared__ float vsl[NB][KK];      // 20 KB
    __shared__ float bl[BCH][JT][12];
    __shared__ float cl[BCH][JT][12];

    const int t   = threadIdx.x;
    const int jj  = t & 15;            // j within tile
    const int k4  = t >> 4;            // float4 chunk of k, 0..39
    const int nB  = k4 >> 2;           // cap index
    const int c4  = k4 & 3;            // c-quad within cap (lane bits 4,5)
    const int j0  = blockIdx.x * JT;

    // ---- W -> registers, once ----
    float4 w[8];
    {
        const float* wp = W + ((size_t)(j0 + jj) * 8) * KK + (k4 << 2);
        #pragma unroll
        for (int i = 0; i < 8; ++i)
            w[i] = *(const float4*)(wp + i * KK);
    }
    // ---- x tile -> LDS ----
    for (int e4 = t; e4 < NB * JT * 2; e4 += NTHR) {
        const int b = e4 >> 5, rem = e4 & 31, jx = rem >> 1, hf = rem & 1;
        const float4 v = *(const float4*)(x + ((size_t)b * NJ + j0 + jx) * 8 + hf * 4);
        float* d = &xs[b][jx][hf * 4];
        d[0] = v.x; d[1] = v.y; d[2] = v.z; d[3] = v.w;
    }
    // ---- vsum -> LDS (R>0) ----
    if (R > 0) {
        for (int f4 = t; f4 < NB * 40; f4 += NTHR) {
            const int b = f4 / 40, rem = f4 % 40;
            *(float4*)&vsl[b][rem * 4] = *(const float4*)(vsum + (size_t)b * KK + rem * 4);
        }
    }
    __syncthreads();

    for (int b0 = 0; b0 < NB; b0 += BCH) {
        // ---- A: u quads in registers ----
        float4 u[BCH];
        #pragma unroll
        for (int bc = 0; bc < BCH; ++bc) {
            const int b = b0 + bc;
            float4 acc = {0.f, 0.f, 0.f, 0.f};
            #pragma unroll
            for (int seg = 0; seg < 4; ++seg) {
                const float2 xv = *(const float2*)&xs[b][jj][seg * 2];
                const float4 wa = w[seg * 2], wb = w[seg * 2 + 1];
                acc.x = fmaf(wa.x, xv.x, acc.x); acc.y = fmaf(wa.y, xv.x, acc.y);
                acc.z = fmaf(wa.z, xv.x, acc.z); acc.w = fmaf(wa.w, xv.x, acc.w);
                acc.x = fmaf(wb.x, xv.y, acc.x); acc.y = fmaf(wb.y, xv.y, acc.y);
                acc.z = fmaf(wb.z, xv.y, acc.z); acc.w = fmaf(wb.w, xv.y, acc.w);
            }
            u[bc] = acc;
        }

        if (R > 0) {
            // ---- B: logit = u . vsum, reduce over c4 ----
            #pragma unroll
            for (int bc = 0; bc < BCH; ++bc) {
                const int b = b0 + bc;
                const float4 vv = *(const float4*)&vsl[b][k4 * 4];
                float bd = u[bc].x * vv.x + u[bc].y * vv.y
                         + u[bc].z * vv.z + u[bc].w * vv.w;
                bd += __shfl_xor(bd, 16);
                bd += __shfl_xor(bd, 32);
                if (c4 == 0) bl[bc][jj][nB] = bd;
            }
            __syncthreads();
            // ---- C: softmax over n, 640 = 4bc x 16jj x 10nn threads ----
            {
                const int bcC = t / 160, rem = t % 160;
                const int jjC = rem & 15, nn = rem >> 4;
                float m = -1e30f;
                #pragma unroll
                for (int q = 0; q < NC; ++q) m = fmaxf(m, bl[bcC][jjC][q]);
                float sum = 0.f;
                #pragma unroll
                for (int q = 0; q < NC; ++q) sum += __expf(bl[bcC][jjC][q] - m);
                cl[bcC][jjC][nn] = __expf(bl[bcC][jjC][nn] - m) / sum;
            }
            __syncthreads();
        }

        // ---- D: s partial = sum_jj c*u via DPP ----
        #pragma unroll
        for (int bc = 0; bc < BCH; ++bc) {
            const int b = b0 + bc;
            const float c = (R == 0) ? 0.1f : cl[bc][jj][nB];
            const float sx = red16(u[bc].x * c);
            const float sy = red16(u[bc].y * c);
            const float sz = red16(u[bc].z * c);
            const float sw = red16(u[bc].w * c);
            if (jj == 0) {
                if (ATOM) {
                    float* sp = sdst + ((size_t)(blockIdx.x & (REP - 1)) * NB + b) * KK + (k4 << 2);
                    atomicAdd(sp + 0, sx); atomicAdd(sp + 1, sy);
                    atomicAdd(sp + 2, sz); atomicAdd(sp + 3, sw);
                } else {
                    // plain store: lanes 0,16,32,48 of each wave write one
                    // contiguous 64B line per (b, wave)
                    float4 q; q.x = sx; q.y = sy; q.z = sz; q.w = sw;
                    *(float4*)(sdst + ((size_t)blockIdx.x * NB + b) * KK + (k4 << 2)) = q;
                }
            }
        }
    }
}

// Store path: sum NPART partials (coalesced), +bias, squash.
// MODE: 0 vsum=v, 1 vsum+=v, 2 out=v. Grid: 20 blocks x 1024 threads.
template<int MODE>
__global__ __launch_bounds__(1024)
void reduce_squash(const float* __restrict__ part, const float* __restrict__ biases,
                   float* __restrict__ vsum, float* __restrict__ out) {
    __shared__ float4 red[16][64];     // 16 KB
    const int t   = threadIdx.x;
    const int col = t & 63;            // f4-column within block
    const int pc  = t >> 6;            // 16 partial-chunks of 32
    const int g   = blockIdx.x * 64 + col;   // global f4 index, 0..1279
    const float4* p4 = (const float4*)part;

    float4 acc = {0.f, 0.f, 0.f, 0.f};
    #pragma unroll 4
    for (int p = pc * 32; p < pc * 32 + 32; ++p) {
        const float4 v = p4[(size_t)p * (NB * KK / 4) + g];
        acc.x += v.x; acc.y += v.y; acc.z += v.z; acc.w += v.w;
    }
    red[pc][col] = acc;
    __syncthreads();
    if (pc == 0) {
        #pragma unroll
        for (int q = 1; q < 16; ++q) {
            const float4 v = red[q][col];
            acc.x += v.x; acc.y += v.y; acc.z += v.z; acc.w += v.w;
        }
        const int k4 = g % 40;
        const float4 bb = *(const float4*)(biases + k4 * 4);
        float4 v;
        {
            const float s0 = acc.x + bb.x, n0 = fabsf(s0);
            v.x = (n0 * n0) / (1.f + n0 * n0) / (n0 + EPSQ) * s0;
            const float s1 = acc.y + bb.y, n1 = fabsf(s1);
            v.y = (n1 * n1) / (1.f + n1 * n1) / (n1 + EPSQ) * s1;
            const float s2 = acc.z + bb.z, n2 = fabsf(s2);
            v.z = (n2 * n2) / (1.f + n2 * n2) / (n2 + EPSQ) * s2;
            const float s3 = acc.w + bb.w, n3 = fabsf(s3);
            v.w = (n3 * n3) / (1.f + n3 * n3) / (n3 + EPSQ) * s3;
        }
        if (MODE == 2) {
            ((float4*)out)[g] = v;
        } else if (MODE == 1) {
            float4 o = ((float4*)vsum)[g];
            o.x += v.x; o.y += v.y; o.z += v.z; o.w += v.w;
            ((float4*)vsum)[g] = o;
        } else {
            ((float4*)vsum)[g] = v;
        }
    }
}

// Atomic-fallback squash (sums REP replicas, re-zeroes them).
template<int MODE>
__global__ __launch_bounds__(256)
void squash_kernel(float* __restrict__ s_part, const float* __restrict__ biases,
                   float* __restrict__ vsum, float* __restrict__ out) {
    const int t = blockIdx.x * blockDim.x + threadIdx.x;
    if (t >= NB * KK) return;
    float s = 0.f;
    #pragma unroll
    for (int r = 0; r < REP; ++r) {
        s += s_part[(size_t)r * (NB * KK) + t];
        s_part[(size_t)r * (NB * KK) + t] = 0.f;
    }
    s += biases[t % KK];
    const float n = fabsf(s);
    const float v = (n * n) / (1.f + n * n) / (n + EPSQ) * s;
    if (MODE == 2)      out[t]   = v;
    else if (MODE == 1) vsum[t] += v;
    else                vsum[t]  = v;
}

extern "C" void kernel_launch(void* const* d_in, const int* in_sizes, int n_in,
                              void* d_out, int out_size, void* d_ws, size_t ws_size,
                              hipStream_t stream) {
    const float* x      = (const float*)d_in[0];
    const float* W      = (const float*)d_in[1];
    const float* biases = (const float*)d_in[2];
    float* out = (float*)d_out;

    const size_t store_need = ((size_t)NPART * NB * KK + NB * KK) * sizeof(float);
    const dim3 grid(NJ / JT);   // 512 blocks

    if (ws_size >= store_need) {
        // ---- no-atomic path: block-private partials + tree reduce ----
        float* part = (float*)d_ws;                        // [NPART][NB*KK]
        float* vsum = part + (size_t)NPART * NB * KK;      // [NB*KK]

        rout_kernel<0, false><<<grid, NTHR, 0, stream>>>(x, W, nullptr, part);
        reduce_squash<0><<<20, 1024, 0, stream>>>(part, biases, vsum, out);

        rout_kernel<1, false><<<grid, NTHR, 0, stream>>>(x, W, vsum, part);
        reduce_squash<1><<<20, 1024, 0, stream>>>(part, biases, vsum, out);

        rout_kernel<2, false><<<grid, NTHR, 0, stream>>>(x, W, vsum, part);
        reduce_squash<2><<<20, 1024, 0, stream>>>(part, biases, vsum, out);
    } else {
        // ---- fallback: replicated atomics (round-3 behavior) ----
        float* s_part = (float*)d_ws;                      // [REP][NB*KK]
        float* vsum   = s_part + (size_t)REP * NB * KK;    // [NB*KK]

        hipMemsetAsync(s_part, 0, (size_t)REP * NB * KK * sizeof(float), stream);

        rout_kernel<0, true><<<grid, NTHR, 0, stream>>>(x, W, nullptr, s_part);
        squash_kernel<0><<<20, 256, 0, stream>>>(s_part, biases, vsum, out);

        rout_kernel<1, true><<<grid, NTHR, 0, stream>>>(x, W, vsum, s_part);
        squash_kernel<1><<<20, 256, 0, stream>>>(s_part, biases, vsum, out);

        rout_kernel<2, true><<<grid, NTHR, 0, stream>>>(x, W, vsum, s_part);
        squash_kernel<2><<<20, 256, 0, stream>>>(s_part, biases, vsum, out);
    }
}